// Round 8
// baseline (561.636 us; speedup 1.0000x reference)
//
#include <hip/hip_runtime.h>
#include <hip/hip_bf16.h>
#include <math.h>

// Problem constants (B=2, S=2048, D=1024, H=16, DH=64)
#define BB 2
#define SS 2048
#define DD 1024
#define HH 16
#define DH 64
#define NTOK (BB * SS)   // 4096
#define LN_EPS 1e-5f
#define BIGNEG -1e30f

typedef __attribute__((ext_vector_type(8))) short bf16x8;   // 8 bf16 = 4 VGPRs
typedef __attribute__((ext_vector_type(4))) float f32x4;    // MFMA accumulator

static __device__ __forceinline__ float b2f(unsigned short u) {
    return __uint_as_float(((unsigned)u) << 16);
}
static __device__ __forceinline__ unsigned short f2bu(float f) {
    __hip_bfloat16 h = __float2bfloat16(f);
    return *(unsigned short*)&h;
}

// async 16B global -> LDS. LDS dest is wave-uniform base + lane*16 by construction.
static __device__ __forceinline__ void async16(const void* g, void* l) {
    __builtin_amdgcn_global_load_lds((const __attribute__((address_space(1))) void*)g,
                                     (__attribute__((address_space(3))) void*)l, 16, 0, 0);
}

// XOR-swizzle: DMA-staged LDS rows are 128B/256B apart (bank 0 every row).
// Store chunk (row, d) at (row, d ^ (row&7)), read back at d ^ (row&7):
// the 16 l15-lanes of a b128 read spread over all 8 4-bank groups (2-way, free).

// ---------------------------------------------------------------------------
// Merged weight transpose+cast for all 6 weights: one launch, 10240 tiles.
// ---------------------------------------------------------------------------
__global__ __launch_bounds__(256) void transpose_all(const float* __restrict__ Wq,
                                                     const float* __restrict__ Wk,
                                                     const float* __restrict__ Wv,
                                                     const float* __restrict__ Wo,
                                                     const float* __restrict__ W1,
                                                     const float* __restrict__ W2,
                                                     __hip_bfloat16* __restrict__ wqkvt,
                                                     __hip_bfloat16* __restrict__ wot,
                                                     __hip_bfloat16* __restrict__ w1t,
                                                     __hip_bfloat16* __restrict__ w2t) {
    const int bid = blockIdx.x;
    const float* W;
    __hip_bfloat16* Wt;
    int K, N, tile;
    if (bid < 4096) {
        const int m = bid >> 10;
        tile = bid & 1023;
        W = (m == 0) ? Wq : (m == 1) ? Wk : (m == 2) ? Wv : Wo;
        Wt = (m < 3) ? (wqkvt + (size_t)m * 1024 * 1024) : wot;
        K = 1024; N = 1024;
    } else if (bid < 8192) {
        tile = bid - 4096; W = W1; Wt = w1t; K = 1024; N = 4096;
    } else {
        tile = bid - 8192; W = W2; Wt = w2t; K = 2048; N = 1024;
    }
    const int nt = N >> 5;
    const int n0 = (tile % nt) * 32, k0 = (tile / nt) * 32;

    __shared__ float t[32][33];
    const int tx = threadIdx.x & 31, ty = threadIdx.x >> 5;
#pragma unroll
    for (int i = 0; i < 4; ++i)
        t[ty + 8 * i][tx] = W[(size_t)(k0 + ty + 8 * i) * N + n0 + tx];
    __syncthreads();
#pragma unroll
    for (int i = 0; i < 4; ++i)
        Wt[(size_t)(n0 + ty + 8 * i) * K + k0 + tx] = __float2bfloat16(t[tx][ty + 8 * i]);
}

// ---------------------------------------------------------------------------
// LayerNorm fp32 -> bf16. One block per row, D=1024.
// ---------------------------------------------------------------------------
__global__ __launch_bounds__(256) void ln_kernel(const float* __restrict__ x,
                                                 const float* __restrict__ gamma,
                                                 const float* __restrict__ beta,
                                                 __hip_bfloat16* __restrict__ out) {
    const int row = blockIdx.x;
    const int tid = threadIdx.x;
    __shared__ float red[256];

    const float* xp = x + (size_t)row * DD;
    float vals[4];
    float s = 0.f;
#pragma unroll
    for (int i = 0; i < 4; ++i) {
        float v = xp[tid + i * 256];
        vals[i] = v;
        s += v;
    }
    red[tid] = s;
    __syncthreads();
    for (int st = 128; st > 0; st >>= 1) {
        if (tid < st) red[tid] += red[tid + st];
        __syncthreads();
    }
    const float mu = red[0] * (1.0f / DD);
    __syncthreads();
    float sq = 0.f;
#pragma unroll
    for (int i = 0; i < 4; ++i) {
        float d = vals[i] - mu;
        sq += d * d;
    }
    red[tid] = sq;
    __syncthreads();
    for (int st = 128; st > 0; st >>= 1) {
        if (tid < st) red[tid] += red[tid + st];
        __syncthreads();
    }
    const float rinv = rsqrtf(red[0] * (1.0f / DD) + LN_EPS);

    __hip_bfloat16* op = out + (size_t)row * DD;
#pragma unroll
    for (int i = 0; i < 4; ++i) {
        int j = tid + i * 256;
        op[j] = __float2bfloat16(gamma[j] * ((vals[i] - mu) * rinv) + beta[j]);
    }
}

// ---------------------------------------------------------------------------
// MFMA bf16 GEMM (m97 structure + XOR-swizzled LDS staging).
// C[M,N] = A[M,K] @ Bt[N,K]^T. 128x128 tile, 4 waves, BK=64.
// RES: 0 none, 1 add fp32 res[oi].
// EPI: 0 fp32 out, 1 bf16 out,
//      3 qkv-split: cols<2048 -> out (bf16, stride 2048);
//                   cols>=2048 (V) -> res as VT bf16 [1024][4096] transposed.
// ---------------------------------------------------------------------------
template <int RES, int EPI>
__global__ __launch_bounds__(256) void mfma_gemm(const __hip_bfloat16* __restrict__ A,
                                                 const __hip_bfloat16* __restrict__ Bt,
                                                 const void* __restrict__ res,
                                                 void* __restrict__ out,
                                                 int M, int N, int K) {
    __shared__ short As[128 * 64];
    __shared__ short Bs[128 * 64];
    const int tid = threadIdx.x;
    const int lane = tid & 63;
    const int wave = tid >> 6;
    const int row0 = blockIdx.y * 128;
    const int col0 = blockIdx.x * 128;
    const int wr = (wave >> 1) * 64;
    const int wc = (wave & 1) * 64;
    const int l15 = lane & 15;
    const int quad = lane >> 4;
    const int s7 = l15 & 7;

    f32x4 acc[4][4] = {};

    for (int k0 = 0; k0 < K; k0 += 64) {
#pragma unroll
        for (int r = 0; r < 4; ++r) {
            const int ec = r * 256 + tid;
            const int ar = ec >> 3, d = ec & 7;
            const int ao = (d ^ (ar & 7)) << 3;     // swizzled source dim offset
            async16(&A[(size_t)(row0 + ar) * K + k0 + ao], &As[ec << 3]);
            async16(&Bt[(size_t)(col0 + ar) * K + k0 + ao], &Bs[ec << 3]);
        }
        __syncthreads();
#pragma unroll
        for (int kk = 0; kk < 2; ++kk) {
            const int co = (((kk << 2) | quad) ^ s7) << 3;  // swizzled chunk offset
            bf16x8 af[4], bfr[4];
#pragma unroll
            for (int i = 0; i < 4; ++i)
                af[i] = *(const bf16x8*)&As[(wr + i * 16 + l15) * 64 + co];
#pragma unroll
            for (int j = 0; j < 4; ++j)
                bfr[j] = *(const bf16x8*)&Bs[(wc + j * 16 + l15) * 64 + co];
#pragma unroll
            for (int i = 0; i < 4; ++i)
#pragma unroll
                for (int j = 0; j < 4; ++j)
                    acc[i][j] = __builtin_amdgcn_mfma_f32_16x16x32_bf16(af[i], bfr[j], acc[i][j], 0, 0, 0);
        }
        __syncthreads();
    }

    const int r4 = quad * 4;
#pragma unroll
    for (int i = 0; i < 4; ++i) {
#pragma unroll
        for (int j = 0; j < 4; ++j) {
            const int orow0 = row0 + wr + i * 16 + r4;
            const int ocol = col0 + wc + j * 16 + l15;
            if constexpr (EPI == 3) {
                if (ocol < 2048) {
#pragma unroll
                    for (int rg = 0; rg < 4; ++rg)
                        ((__hip_bfloat16*)out)[(size_t)(orow0 + rg) * 2048 + ocol] =
                            __float2bfloat16(acc[i][j][rg]);
                } else {
                    ushort4 u;
                    u.x = f2bu(acc[i][j][0]);
                    u.y = f2bu(acc[i][j][1]);
                    u.z = f2bu(acc[i][j][2]);
                    u.w = f2bu(acc[i][j][3]);
                    *(ushort4*)((unsigned short*)res + (size_t)(ocol - 2048) * 4096 + orow0) = u;
                }
            } else {
#pragma unroll
                for (int rg = 0; rg < 4; ++rg) {
                    const size_t oi = (size_t)(orow0 + rg) * N + ocol;
                    float v = acc[i][j][rg];
                    if constexpr (RES == 1) v += ((const float*)res)[oi];
                    if constexpr (EPI == 0) ((float*)out)[oi] = v;
                    if constexpr (EPI == 1) ((__hip_bfloat16*)out)[oi] = __float2bfloat16(v);
                }
            }
        }
    }
}

// ---------------------------------------------------------------------------
// Fused FFN-in GEMM+GLU (swizzled staging): glu = (A@W1L^T) * sigmoid(A@W1R^T).
// ---------------------------------------------------------------------------
__global__ __launch_bounds__(256) void mfma_gemm_glu(const __hip_bfloat16* __restrict__ A,
                                                     const __hip_bfloat16* __restrict__ Bt,
                                                     __hip_bfloat16* __restrict__ out) {
    __shared__ short As[128 * 64];
    __shared__ short Bl[128 * 64];
    __shared__ short Br[128 * 64];
    const int tid = threadIdx.x;
    const int lane = tid & 63;
    const int wave = tid >> 6;
    const int row0 = blockIdx.y * 128;
    const int col0 = blockIdx.x * 128;
    const int wr = (wave >> 1) * 64;
    const int wc = (wave & 1) * 64;
    const int l15 = lane & 15;
    const int quad = lane >> 4;
    const int s7 = l15 & 7;

    f32x4 accl[4][4] = {};
    f32x4 accr[4][4] = {};

    for (int k0 = 0; k0 < 1024; k0 += 64) {
#pragma unroll
        for (int r = 0; r < 4; ++r) {
            const int ec = r * 256 + tid;
            const int ar = ec >> 3, d = ec & 7;
            const int ao = (d ^ (ar & 7)) << 3;
            async16(&A[(size_t)(row0 + ar) * 1024 + k0 + ao], &As[ec << 3]);
            async16(&Bt[(size_t)(col0 + ar) * 1024 + k0 + ao], &Bl[ec << 3]);
            async16(&Bt[(size_t)(2048 + col0 + ar) * 1024 + k0 + ao], &Br[ec << 3]);
        }
        __syncthreads();
#pragma unroll
        for (int kk = 0; kk < 2; ++kk) {
            const int co = (((kk << 2) | quad) ^ s7) << 3;
            bf16x8 af[4], bl[4], br[4];
#pragma unroll
            for (int i = 0; i < 4; ++i)
                af[i] = *(const bf16x8*)&As[(wr + i * 16 + l15) * 64 + co];
#pragma unroll
            for (int j = 0; j < 4; ++j) {
                bl[j] = *(const bf16x8*)&Bl[(wc + j * 16 + l15) * 64 + co];
                br[j] = *(const bf16x8*)&Br[(wc + j * 16 + l15) * 64 + co];
            }
#pragma unroll
            for (int i = 0; i < 4; ++i)
#pragma unroll
                for (int j = 0; j < 4; ++j) {
                    accl[i][j] = __builtin_amdgcn_mfma_f32_16x16x32_bf16(af[i], bl[j], accl[i][j], 0, 0, 0);
                    accr[i][j] = __builtin_amdgcn_mfma_f32_16x16x32_bf16(af[i], br[j], accr[i][j], 0, 0, 0);
                }
        }
        __syncthreads();
    }

    const int r4 = quad * 4;
#pragma unroll
    for (int i = 0; i < 4; ++i) {
#pragma unroll
        for (int j = 0; j < 4; ++j) {
#pragma unroll
            for (int rg = 0; rg < 4; ++rg) {
                const int orow = row0 + wr + i * 16 + r4 + rg;
                const int ocol = col0 + wc + j * 16 + l15;
                const float l = accl[i][j][rg];
                const float r = accr[i][j][rg];
                out[(size_t)orow * 2048 + ocol] =
                    __float2bfloat16(l * (1.f / (1.f + __expf(-r))));
            }
        }
    }
}

// ---------------------------------------------------------------------------
// MFMA flash attention v5. Tq=128 (wave owns 32 q = 2 tiles), Tk=128 chunks.
// XCD-aware block mapping: all 16 qt-blocks of a (b,h) land on one XCD
// (blockIdx%8 -> XCD round-robin heuristic) so K/V re-reads hit that XCD's L2
// (hot set 4 bh x 1 MB = 4 MB). Swizzled DMA staging (conflict-free b128
// reads); per-wave P buffer (wave-private, no extra barriers); q-tiles
// processed sequentially to halve S register pressure.
// ---------------------------------------------------------------------------
__global__ __launch_bounds__(256, 3) void flash_mfma(const __hip_bfloat16* __restrict__ qkb_,
                                                     const __hip_bfloat16* __restrict__ VT_,
                                                     const int* __restrict__ mask,
                                                     __hip_bfloat16* __restrict__ attnb) {
    const unsigned short* qkb = (const unsigned short*)qkb_;
    const unsigned short* VT = (const unsigned short*)VT_;
    __shared__ __align__(16) short Ks[128 * 64];    // [key][dim], swizzled
    __shared__ __align__(16) short Vt[64 * 128];    // [dim][key], swizzled
    __shared__ __align__(16) short Ps[4][16 * 128]; // per-wave P (one q-tile at a time)
    __shared__ float bias[128];

    const int tid = threadIdx.x;
    const int lane = tid & 63;
    const int wave = tid >> 6;
    const int l15 = lane & 15;
    const int quad = lane >> 4;
    const int s7 = l15 & 7;

    // XCD-aware decode: xcd = blockIdx%8; 4 bh per xcd; qt reversed (long first)
    const int xcd = blockIdx.x & 7;
    const int slot = blockIdx.x >> 3;          // 0..63
    const int bh = xcd + ((slot & 3) << 3);    // 0..31
    const int qt = 15 - (slot >> 2);           // 0..15
    const int h = bh & 15;
    const int b = bh >> 4;
    const int q0 = qt * 128 + wave * 32;       // wave's first query

    // Q fragments (A-layout) for both q-tiles
    bf16x8 aq[2][2];
#pragma unroll
    for (int t = 0; t < 2; ++t)
#pragma unroll
        for (int ks = 0; ks < 2; ++ks)
            aq[t][ks] = *(const bf16x8*)(qkb + (size_t)(b * SS + q0 + t * 16 + l15) * 2048 +
                                         h * 64 + ks * 32 + quad * 8);

    f32x4 O[2][4];
    float m_r[2][4], l_r[2][4];
#pragma unroll
    for (int t = 0; t < 2; ++t)
#pragma unroll
        for (int i = 0; i < 4; ++i) {
            O[t][i] = (f32x4){0.f, 0.f, 0.f, 0.f};
            m_r[t][i] = BIGNEG;
            l_r[t][i] = 0.f;
        }

    const int nch = qt + 1;                    // 128-key chunks
    for (int c = 0; c < nch; ++c) {
        const int kb = c << 7;
        __syncthreads();  // prev-iter Ks/Vt reads done before DMA overwrite
        // stage K: 128 keys x 64 dims, swizzled chunks (4 rounds x 256 x 16B)
#pragma unroll
        for (int r = 0; r < 4; ++r) {
            const int e = r * 256 + tid;
            const int key = e >> 3, d = e & 7;
            async16(qkb + (size_t)(b * SS + kb + key) * 2048 + 1024 + h * 64 +
                        ((d ^ (key & 7)) << 3),
                    &Ks[e << 3]);
        }
        // stage V^T: 64 dims x 128 keys from VT, swizzled chunks
#pragma unroll
        for (int r = 0; r < 4; ++r) {
            const int e = r * 256 + tid;
            const int dim = e >> 4, kc = e & 15;
            async16(VT + (size_t)(h * 64 + dim) * 4096 + b * SS + kb +
                        ((kc ^ (dim & 7)) << 3),
                    &Vt[e << 3]);
        }
        if (tid < 128) bias[tid] = mask[b * SS + kb + tid] ? 0.f : BIGNEG;
        __syncthreads();

        const bool diag = (c == qt);
        short* Pw = &Ps[wave][0];

#pragma unroll
        for (int t = 0; t < 2; ++t) {
            const int ktmax = diag ? (wave * 2 + t + 1) : 8;
            const int ktfull = diag ? (wave * 2 + t) : 8;

            // ---- S = Q K^T for live tiles
            f32x4 S[8];
#pragma unroll
            for (int kt = 0; kt < 8; ++kt) {
                if (kt >= ktmax) break;
                const bf16x8 bk0 = *(const bf16x8*)&Ks[(kt * 16 + l15) * 64 + ((quad ^ s7) << 3)];
                const bf16x8 bk1 = *(const bf16x8*)&Ks[(kt * 16 + l15) * 64 + (((4 | quad) ^ s7) << 3)];
                f32x4 z = {0.f, 0.f, 0.f, 0.f};
                z = __builtin_amdgcn_mfma_f32_16x16x32_bf16(aq[t][0], bk0, z, 0, 0, 0);
                S[kt] = __builtin_amdgcn_mfma_f32_16x16x32_bf16(aq[t][1], bk1, z, 0, 0, 0);
            }
            // ---- scale + mask-bias + (diagonal-only) causal
#pragma unroll
            for (int kt = 0; kt < 8; ++kt) {
                if (kt >= ktmax) break;
                const float bv = bias[kt * 16 + l15];
#pragma unroll
                for (int rg = 0; rg < 4; ++rg) {
                    float s = fmaf(S[kt][rg], 0.125f, bv);
                    if (kt >= ktfull) {
                        const int key = kb + kt * 16 + l15;
                        const int qrow = q0 + t * 16 + quad * 4 + rg;
                        s = (key <= qrow) ? s : BIGNEG;
                    }
                    S[kt][rg] = s;
                }
            }
            // ---- online softmax (16-lane row reductions)
            float alpha[4];
#pragma unroll
            for (int rg = 0; rg < 4; ++rg) {
                float v = BIGNEG;
#pragma unroll
                for (int kt = 0; kt < 8; ++kt)
                    if (kt < ktmax) v = fmaxf(v, S[kt][rg]);
                v = fmaxf(v, __shfl_xor(v, 1));
                v = fmaxf(v, __shfl_xor(v, 2));
                v = fmaxf(v, __shfl_xor(v, 4));
                v = fmaxf(v, __shfl_xor(v, 8));
                const float mn = fmaxf(m_r[t][rg], v);
                alpha[rg] = __expf(m_r[t][rg] - mn);
                m_r[t][rg] = mn;
                l_r[t][rg] *= alpha[rg];
            }
#pragma unroll
            for (int kt = 0; kt < 8; ++kt) {
                if (kt >= ktmax) break;
#pragma unroll
                for (int rg = 0; rg < 4; ++rg)
                    S[kt][rg] = __expf(S[kt][rg] - m_r[t][rg]);
            }
#pragma unroll
            for (int rg = 0; rg < 4; ++rg) {
                float v = 0.f;
#pragma unroll
                for (int kt = 0; kt < 8; ++kt)
                    if (kt < ktmax) v += S[kt][rg];
                v += __shfl_xor(v, 1);
                v += __shfl_xor(v, 2);
                v += __shfl_xor(v, 4);
                v += __shfl_xor(v, 8);
                l_r[t][rg] += v;
            }
            // ---- rescale O
#pragma unroll
            for (int nt = 0; nt < 4; ++nt)
#pragma unroll
                for (int rg = 0; rg < 4; ++rg)
                    O[t][nt][rg] *= alpha[rg];

            // ---- P: C-layout regs -> per-wave swizzled LDS (wave-private,
            // same-wave DS ordering + lgkmcnt(0) makes reuse across t safe)
            asm volatile("s_waitcnt lgkmcnt(0)" ::: "memory");
#pragma unroll
            for (int kt = 0; kt < 8; ++kt) {
                if (kt >= ktmax) break;
#pragma unroll
                for (int rg = 0; rg < 4; ++rg) {
                    const int qr = quad * 4 + rg;
                    const int ch = (kt * 2) | (l15 >> 3);
                    Pw[(qr << 7) + (((ch ^ (qr & 7)) << 3) | s7)] = (short)f2bu(S[kt][rg]);
                }
            }
            const int kkmax = (ktmax + 1) >> 1;
            if (ktmax & 1) {   // zero-fill phantom tile so PV runs in 32-key steps
#pragma unroll
                for (int rg = 0; rg < 4; ++rg) {
                    const int qr = quad * 4 + rg;
                    const int ch = (ktmax * 2) | (l15 >> 3);
                    Pw[(qr << 7) + (((ch ^ (qr & 7)) << 3) | s7)] = 0;
                }
            }
            asm volatile("s_waitcnt lgkmcnt(0)" ::: "memory");
            // ---- O += P V
#pragma unroll
            for (int kk = 0; kk < 4; ++kk) {
                if (kk >= kkmax) break;
                const bf16x8 ap = *(const bf16x8*)&Pw[(l15 << 7) + ((((kk << 2) | quad) ^ s7) << 3)];
#pragma unroll
                for (int nt = 0; nt < 4; ++nt) {
                    const bf16x8 bv = *(const bf16x8*)&Vt[(nt * 16 + l15) * 128 +
                                                         ((((kk << 2) | quad) ^ s7) << 3)];
                    O[t][nt] = __builtin_amdgcn_mfma_f32_16x16x32_bf16(ap, bv, O[t][nt], 0, 0, 0);
                }
            }
        }
    }

    // epilogue: O /= l, write bf16
#pragma unroll
    for (int t = 0; t < 2; ++t)
#pragma unroll
        for (int rg = 0; rg < 4; ++rg) {
            const int q = q0 + t * 16 + quad * 4 + rg;
            const float inv = 1.f / l_r[t][rg];
            unsigned short* op = (unsigned short*)attnb + (size_t)(b * SS + q) * 1024 + h * 64;
#pragma unroll
            for (int nt = 0; nt < 4; ++nt)
                op[nt * 16 + l15] = f2bu(O[t][nt][rg] * inv);
        }
}

// ---------------------------------------------------------------------------
// Launch. Workspace plan (60 MB peak), offsets in bytes:
//   [0,6M)   Wqkv_t bf16 [3072][1024]
//   [6,8M)   Wo_t   bf16 [1024][1024]
//   [8,16M)  W1_t   bf16 [4096][1024]
//   [16,20M) W2_t   bf16 [1024][2048]
//   [20,28M) lnb    bf16 (ln1 then ln2)
//   [28,44M) qkb    bf16 [4096][2048] (q|k)  -> dead after flash
//   [44,52M) VT     bf16 [1024][4096] (v^T)  -> dead after flash
//   [52,60M) attnb  bf16                     -> dead after Wo gemm
//   [28,44M) x1     fp32 (reuses qkb)
//   [44,52M) glub   bf16 (reuses VT)
// ---------------------------------------------------------------------------
extern "C" void kernel_launch(void* const* d_in, const int* in_sizes, int n_in,
                              void* d_out, int out_size, void* d_ws, size_t ws_size,
                              hipStream_t stream) {
    const float* x  = (const float*)d_in[0];
    const int* mask = (const int*)d_in[1];
    const float* Wq = (const float*)d_in[2];
    const float* Wk = (const float*)d_in[3];
    const float* Wv = (const float*)d_in[4];
    const float* Wo = (const float*)d_in[5];
    const float* W1 = (const float*)d_in[6];
    const float* W2 = (const float*)d_in[7];
    const float* g1 = (const float*)d_in[8];
    const float* b1 = (const float*)d_in[9];
    const float* g2 = (const float*)d_in[10];
    const float* b2 = (const float*)d_in[11];

    const size_t MB = 1024 * 1024;
    uint8_t* ws = (uint8_t*)d_ws;
    __hip_bfloat16* wqkvt = (__hip_bfloat16*)(ws);
    __hip_bfloat16* wot   = (__hip_bfloat16*)(ws + 6 * MB);
    __hip_bfloat16* w1t   = (__hip_bfloat16*)(ws + 8 * MB);
    __hip_bfloat16* w2t   = (__hip_bfloat16*)(ws + 16 * MB);
    __hip_bfloat16* lnb   = (__hip_bfloat16*)(ws + 20 * MB);
    __hip_bfloat16* qkb   = (__hip_bfloat16*)(ws + 28 * MB);
    float*          x1    = (float*)(ws + 28 * MB);
    __hip_bfloat16* VT    = (__hip_bfloat16*)(ws + 44 * MB);
    __hip_bfloat16* glub  = (__hip_bfloat16*)(ws + 44 * MB);
    __hip_bfloat16* attnb = (__hip_bfloat16*)(ws + 52 * MB);

    // 0. all weight transposes in one launch
    transpose_all<<<10240, 256, 0, stream>>>(Wq, Wk, Wv, Wo, W1, W2, wqkvt, wot, w1t, w2t);

    // 1. ln1 = LN(x) -> lnb
    ln_kernel<<<NTOK, 256, 0, stream>>>(x, g1, b1, lnb);

    // 2. qkv GEMM: q,k -> qkb; v -> VT (transposed)
    mfma_gemm<0, 3><<<dim3(24, 32), 256, 0, stream>>>(lnb, wqkvt, VT, qkb, NTOK, 3072, 1024);

    // 3. MFMA flash attention -> attnb (512 blocks, XCD-aware)
    flash_mfma<<<512, 256, 0, stream>>>(qkb, VT, mask, attnb);

    // 4. x1 = x + attn @ Wo -> x1 (fp32)
    mfma_gemm<1, 0><<<dim3(8, 32), 256, 0, stream>>>(attnb, wot, x, x1, NTOK, 1024, 1024);

    // 5. ln2 = LN(x1) -> lnb
    ln_kernel<<<NTOK, 256, 0, stream>>>(x1, g2, b2, lnb);

    // 6. glu = (ln2@W1L) * sigmoid(ln2@W1R) -> glub
    mfma_gemm_glu<<<dim3(16, 32), 256, 0, stream>>>(lnb, w1t, glub);

    // 7. out = x1 + glu @ W2 -> d_out (fp32)
    mfma_gemm<1, 0><<<dim3(8, 32), 256, 0, stream>>>(glub, w2t, x1, (float*)d_out,
                                                     NTOK, 1024, 2048);
}

// Round 9
// 351.392 us; speedup vs baseline: 1.5983x; 1.5983x over previous
//
#include <hip/hip_runtime.h>
#include <hip/hip_bf16.h>
#include <math.h>

// Problem constants (B=2, S=2048, D=1024, H=16, DH=64)
#define BB 2
#define SS 2048
#define DD 1024
#define HH 16
#define DH 64
#define NTOK (BB * SS)   // 4096
#define LN_EPS 1e-5f
#define BIGNEG -1e30f

typedef __attribute__((ext_vector_type(8))) short bf16x8;   // 8 bf16 = 4 VGPRs
typedef __attribute__((ext_vector_type(4))) float f32x4;    // MFMA accumulator

static __device__ __forceinline__ float b2f(unsigned short u) {
    return __uint_as_float(((unsigned)u) << 16);
}
static __device__ __forceinline__ unsigned short f2bu(float f) {
    __hip_bfloat16 h = __float2bfloat16(f);
    return *(unsigned short*)&h;
}

// async 16B global -> LDS. LDS dest is wave-uniform base + lane*16 by construction.
static __device__ __forceinline__ void async16(const void* g, void* l) {
    __builtin_amdgcn_global_load_lds((const __attribute__((address_space(1))) void*)g,
                                     (__attribute__((address_space(3))) void*)l, 16, 0, 0);
}

// XOR-swizzle: DMA-staged LDS rows are 128B apart (bank 0 every row).
// Store chunk (row, d) at (row, d ^ (row&7)), read back at d ^ (row&7):
// the 16 l15-lanes of a b128 read spread over all 8 4-bank groups (2-way, free).

// ---------------------------------------------------------------------------
// Merged weight transpose+cast for all 6 weights: one launch, 10240 tiles.
// ---------------------------------------------------------------------------
__global__ __launch_bounds__(256) void transpose_all(const float* __restrict__ Wq,
                                                     const float* __restrict__ Wk,
                                                     const float* __restrict__ Wv,
                                                     const float* __restrict__ Wo,
                                                     const float* __restrict__ W1,
                                                     const float* __restrict__ W2,
                                                     __hip_bfloat16* __restrict__ wqkvt,
                                                     __hip_bfloat16* __restrict__ wot,
                                                     __hip_bfloat16* __restrict__ w1t,
                                                     __hip_bfloat16* __restrict__ w2t) {
    const int bid = blockIdx.x;
    const float* W;
    __hip_bfloat16* Wt;
    int K, N, tile;
    if (bid < 4096) {
        const int m = bid >> 10;
        tile = bid & 1023;
        W = (m == 0) ? Wq : (m == 1) ? Wk : (m == 2) ? Wv : Wo;
        Wt = (m < 3) ? (wqkvt + (size_t)m * 1024 * 1024) : wot;
        K = 1024; N = 1024;
    } else if (bid < 8192) {
        tile = bid - 4096; W = W1; Wt = w1t; K = 1024; N = 4096;
    } else {
        tile = bid - 8192; W = W2; Wt = w2t; K = 2048; N = 1024;
    }
    const int nt = N >> 5;
    const int n0 = (tile % nt) * 32, k0 = (tile / nt) * 32;

    __shared__ float t[32][33];
    const int tx = threadIdx.x & 31, ty = threadIdx.x >> 5;
#pragma unroll
    for (int i = 0; i < 4; ++i)
        t[ty + 8 * i][tx] = W[(size_t)(k0 + ty + 8 * i) * N + n0 + tx];
    __syncthreads();
#pragma unroll
    for (int i = 0; i < 4; ++i)
        Wt[(size_t)(n0 + ty + 8 * i) * K + k0 + tx] = __float2bfloat16(t[tx][ty + 8 * i]);
}

// ---------------------------------------------------------------------------
// LayerNorm fp32 -> bf16. One block per row, D=1024.
// ---------------------------------------------------------------------------
__global__ __launch_bounds__(256) void ln_kernel(const float* __restrict__ x,
                                                 const float* __restrict__ gamma,
                                                 const float* __restrict__ beta,
                                                 __hip_bfloat16* __restrict__ out) {
    const int row = blockIdx.x;
    const int tid = threadIdx.x;
    __shared__ float red[256];

    const float* xp = x + (size_t)row * DD;
    float vals[4];
    float s = 0.f;
#pragma unroll
    for (int i = 0; i < 4; ++i) {
        float v = xp[tid + i * 256];
        vals[i] = v;
        s += v;
    }
    red[tid] = s;
    __syncthreads();
    for (int st = 128; st > 0; st >>= 1) {
        if (tid < st) red[tid] += red[tid + st];
        __syncthreads();
    }
    const float mu = red[0] * (1.0f / DD);
    __syncthreads();
    float sq = 0.f;
#pragma unroll
    for (int i = 0; i < 4; ++i) {
        float d = vals[i] - mu;
        sq += d * d;
    }
    red[tid] = sq;
    __syncthreads();
    for (int st = 128; st > 0; st >>= 1) {
        if (tid < st) red[tid] += red[tid + st];
        __syncthreads();
    }
    const float rinv = rsqrtf(red[0] * (1.0f / DD) + LN_EPS);

    __hip_bfloat16* op = out + (size_t)row * DD;
#pragma unroll
    for (int i = 0; i < 4; ++i) {
        int j = tid + i * 256;
        op[j] = __float2bfloat16(gamma[j] * ((vals[i] - mu) * rinv) + beta[j]);
    }
}

// ---------------------------------------------------------------------------
// MFMA bf16 GEMM (m97 structure + XOR-swizzled LDS staging).
// C[M,N] = A[M,K] @ Bt[N,K]^T. 128x128 tile, 4 waves, BK=64.
// RES: 0 none, 1 add fp32 res[oi].
// EPI: 0 fp32 out, 1 bf16 out,
//      3 qkv-split: cols<2048 -> out (bf16, stride 2048);
//                   cols>=2048 (V) -> res as VT bf16 [1024][4096] transposed.
// ---------------------------------------------------------------------------
template <int RES, int EPI>
__global__ __launch_bounds__(256) void mfma_gemm(const __hip_bfloat16* __restrict__ A,
                                                 const __hip_bfloat16* __restrict__ Bt,
                                                 const void* __restrict__ res,
                                                 void* __restrict__ out,
                                                 int M, int N, int K) {
    __shared__ short As[128 * 64];
    __shared__ short Bs[128 * 64];
    const int tid = threadIdx.x;
    const int lane = tid & 63;
    const int wave = tid >> 6;
    const int row0 = blockIdx.y * 128;
    const int col0 = blockIdx.x * 128;
    const int wr = (wave >> 1) * 64;
    const int wc = (wave & 1) * 64;
    const int l15 = lane & 15;
    const int quad = lane >> 4;
    const int s7 = l15 & 7;

    f32x4 acc[4][4] = {};

    for (int k0 = 0; k0 < K; k0 += 64) {
#pragma unroll
        for (int r = 0; r < 4; ++r) {
            const int ec = r * 256 + tid;
            const int ar = ec >> 3, d = ec & 7;
            const int ao = (d ^ (ar & 7)) << 3;     // swizzled source dim offset
            async16(&A[(size_t)(row0 + ar) * K + k0 + ao], &As[ec << 3]);
            async16(&Bt[(size_t)(col0 + ar) * K + k0 + ao], &Bs[ec << 3]);
        }
        __syncthreads();
#pragma unroll
        for (int kk = 0; kk < 2; ++kk) {
            const int co = (((kk << 2) | quad) ^ s7) << 3;  // swizzled chunk offset
            bf16x8 af[4], bfr[4];
#pragma unroll
            for (int i = 0; i < 4; ++i)
                af[i] = *(const bf16x8*)&As[(wr + i * 16 + l15) * 64 + co];
#pragma unroll
            for (int j = 0; j < 4; ++j)
                bfr[j] = *(const bf16x8*)&Bs[(wc + j * 16 + l15) * 64 + co];
#pragma unroll
            for (int i = 0; i < 4; ++i)
#pragma unroll
                for (int j = 0; j < 4; ++j)
                    acc[i][j] = __builtin_amdgcn_mfma_f32_16x16x32_bf16(af[i], bfr[j], acc[i][j], 0, 0, 0);
        }
        __syncthreads();
    }

    const int r4 = quad * 4;
#pragma unroll
    for (int i = 0; i < 4; ++i) {
#pragma unroll
        for (int j = 0; j < 4; ++j) {
            const int orow0 = row0 + wr + i * 16 + r4;
            const int ocol = col0 + wc + j * 16 + l15;
            if constexpr (EPI == 3) {
                if (ocol < 2048) {
#pragma unroll
                    for (int rg = 0; rg < 4; ++rg)
                        ((__hip_bfloat16*)out)[(size_t)(orow0 + rg) * 2048 + ocol] =
                            __float2bfloat16(acc[i][j][rg]);
                } else {
                    ushort4 u;
                    u.x = f2bu(acc[i][j][0]);
                    u.y = f2bu(acc[i][j][1]);
                    u.z = f2bu(acc[i][j][2]);
                    u.w = f2bu(acc[i][j][3]);
                    *(ushort4*)((unsigned short*)res + (size_t)(ocol - 2048) * 4096 + orow0) = u;
                }
            } else {
#pragma unroll
                for (int rg = 0; rg < 4; ++rg) {
                    const size_t oi = (size_t)(orow0 + rg) * N + ocol;
                    float v = acc[i][j][rg];
                    if constexpr (RES == 1) v += ((const float*)res)[oi];
                    if constexpr (EPI == 0) ((float*)out)[oi] = v;
                    if constexpr (EPI == 1) ((__hip_bfloat16*)out)[oi] = __float2bfloat16(v);
                }
            }
        }
    }
}

// ---------------------------------------------------------------------------
// Fused FFN-in GEMM+GLU (swizzled staging): glu = (A@W1L^T) * sigmoid(A@W1R^T).
// ---------------------------------------------------------------------------
__global__ __launch_bounds__(256) void mfma_gemm_glu(const __hip_bfloat16* __restrict__ A,
                                                     const __hip_bfloat16* __restrict__ Bt,
                                                     __hip_bfloat16* __restrict__ out) {
    __shared__ short As[128 * 64];
    __shared__ short Bl[128 * 64];
    __shared__ short Br[128 * 64];
    const int tid = threadIdx.x;
    const int lane = tid & 63;
    const int wave = tid >> 6;
    const int row0 = blockIdx.y * 128;
    const int col0 = blockIdx.x * 128;
    const int wr = (wave >> 1) * 64;
    const int wc = (wave & 1) * 64;
    const int l15 = lane & 15;
    const int quad = lane >> 4;
    const int s7 = l15 & 7;

    f32x4 accl[4][4] = {};
    f32x4 accr[4][4] = {};

    for (int k0 = 0; k0 < 1024; k0 += 64) {
#pragma unroll
        for (int r = 0; r < 4; ++r) {
            const int ec = r * 256 + tid;
            const int ar = ec >> 3, d = ec & 7;
            const int ao = (d ^ (ar & 7)) << 3;
            async16(&A[(size_t)(row0 + ar) * 1024 + k0 + ao], &As[ec << 3]);
            async16(&Bt[(size_t)(col0 + ar) * 1024 + k0 + ao], &Bl[ec << 3]);
            async16(&Bt[(size_t)(2048 + col0 + ar) * 1024 + k0 + ao], &Br[ec << 3]);
        }
        __syncthreads();
#pragma unroll
        for (int kk = 0; kk < 2; ++kk) {
            const int co = (((kk << 2) | quad) ^ s7) << 3;
            bf16x8 af[4], bl[4], br[4];
#pragma unroll
            for (int i = 0; i < 4; ++i)
                af[i] = *(const bf16x8*)&As[(wr + i * 16 + l15) * 64 + co];
#pragma unroll
            for (int j = 0; j < 4; ++j) {
                bl[j] = *(const bf16x8*)&Bl[(wc + j * 16 + l15) * 64 + co];
                br[j] = *(const bf16x8*)&Br[(wc + j * 16 + l15) * 64 + co];
            }
#pragma unroll
            for (int i = 0; i < 4; ++i)
#pragma unroll
                for (int j = 0; j < 4; ++j) {
                    accl[i][j] = __builtin_amdgcn_mfma_f32_16x16x32_bf16(af[i], bl[j], accl[i][j], 0, 0, 0);
                    accr[i][j] = __builtin_amdgcn_mfma_f32_16x16x32_bf16(af[i], br[j], accr[i][j], 0, 0, 0);
                }
        }
        __syncthreads();
    }

    const int r4 = quad * 4;
#pragma unroll
    for (int i = 0; i < 4; ++i) {
#pragma unroll
        for (int j = 0; j < 4; ++j) {
#pragma unroll
            for (int rg = 0; rg < 4; ++rg) {
                const int orow = row0 + wr + i * 16 + r4 + rg;
                const int ocol = col0 + wc + j * 16 + l15;
                const float l = accl[i][j][rg];
                const float r = accr[i][j][rg];
                out[(size_t)orow * 2048 + ocol] =
                    __float2bfloat16(l * (1.f / (1.f + __expf(-r))));
            }
        }
    }
}

// ---------------------------------------------------------------------------
// MFMA flash attention v6. Tq=64 (wave owns 16 q), 4 waves, Tk=64 chunks,
// 1024 blocks. K/V LDS double-buffered: chunk c+1's async16 DMA is issued
// right after the barrier, then chunk c is computed -> the next barrier's
// implicit vmcnt(0) drains a DMA issued one compute-phase earlier (latency
// hidden). ONE barrier per chunk. XOR-swizzled staging (conflict-free b128),
// pre-transposed VT source, full mask->bias row staged once per block,
// XCD-aware block decode (all 32 qt-blocks of a (b,h) on one XCD).
// ---------------------------------------------------------------------------
__global__ __launch_bounds__(256, 3) void flash_mfma(const __hip_bfloat16* __restrict__ qkb_,
                                                     const __hip_bfloat16* __restrict__ VT_,
                                                     const int* __restrict__ mask,
                                                     __hip_bfloat16* __restrict__ attnb) {
    const unsigned short* qkb = (const unsigned short*)qkb_;
    const unsigned short* VT = (const unsigned short*)VT_;
    __shared__ __align__(16) short Ks[2][64 * 64];  // [buf][key][dim], swizzled
    __shared__ __align__(16) short Vt[2][64 * 64];  // [buf][dim][key], swizzled
    __shared__ __align__(16) short Ps[4][16 * 64];  // per-wave P, swizzled
    __shared__ float bias[SS];                      // mask -> additive bias (whole row)

    const int tid = threadIdx.x;
    const int lane = tid & 63;
    const int wave = tid >> 6;
    const int l15 = lane & 15;
    const int quad = lane >> 4;
    const int s7 = l15 & 7;

    // XCD-aware decode: xcd = bid%8; 4 bh per xcd x 32 qt; qt reversed (long first)
    const int xcd = blockIdx.x & 7;
    const int slot = blockIdx.x >> 3;          // 0..127
    const int bh = xcd + ((slot & 3) << 3);    // 0..31
    const int qt = 31 - (slot >> 2);           // 0..31
    const int h = bh & 15;
    const int b = bh >> 4;
    const int q0 = qt * 64 + wave * 16;        // wave's first query

    // mask -> bias row (once per block)
    for (int i = tid; i < SS; i += 256)
        bias[i] = mask[b * SS + i] ? 0.f : BIGNEG;

    // Q fragments (A-layout): m=lane&15 -> query, k=quad*8+j -> dim
    bf16x8 aq[2];
#pragma unroll
    for (int ks = 0; ks < 2; ++ks)
        aq[ks] = *(const bf16x8*)(qkb + (size_t)(b * SS + q0 + l15) * 2048 +
                                  h * 64 + ks * 32 + quad * 8);

    f32x4 O[4];
    float m_r[4], l_r[4];
#pragma unroll
    for (int i = 0; i < 4; ++i) {
        O[i] = (f32x4){0.f, 0.f, 0.f, 0.f};
        m_r[i] = BIGNEG;
        l_r[i] = 0.f;
    }

    const int nch = qt + 1;                    // 64-key chunks

    // stage chunk 0 into buffer 0
    {
#pragma unroll
        for (int r = 0; r < 2; ++r) {
            const int e = r * 256 + tid;
            const int key = e >> 3, dc = e & 7;
            async16(qkb + (size_t)(b * SS + key) * 2048 + 1024 + h * 64 +
                        ((dc ^ (key & 7)) << 3),
                    &Ks[0][e << 3]);
        }
#pragma unroll
        for (int r = 0; r < 2; ++r) {
            const int e = r * 256 + tid;
            const int dim = e >> 3, kc = e & 7;
            async16(VT + (size_t)(h * 64 + dim) * 4096 + b * SS +
                        ((kc ^ (dim & 7)) << 3),
                    &Vt[0][e << 3]);
        }
    }

    for (int c = 0; c < nch; ++c) {
        const int cur = c & 1;
        __syncthreads();   // drains chunk-c DMA (vmcnt0) + chunk-(c-1) LDS reads

        // prefetch chunk c+1 into the other buffer (overlaps with compute below)
        if (c + 1 < nch) {
            const int kb2 = (c + 1) << 6;
#pragma unroll
            for (int r = 0; r < 2; ++r) {
                const int e = r * 256 + tid;
                const int key = e >> 3, dc = e & 7;
                async16(qkb + (size_t)(b * SS + kb2 + key) * 2048 + 1024 + h * 64 +
                            ((dc ^ (key & 7)) << 3),
                        &Ks[1 - cur][e << 3]);
            }
#pragma unroll
            for (int r = 0; r < 2; ++r) {
                const int e = r * 256 + tid;
                const int dim = e >> 3, kc = e & 7;
                async16(VT + (size_t)(h * 64 + dim) * 4096 + b * SS + kb2 +
                            ((kc ^ (dim & 7)) << 3),
                        &Vt[1 - cur][e << 3]);
            }
        }

        const int kb = c << 6;
        const int dq = q0 - kb;
        if (dq + 15 < 0) continue;             // wave fully above diagonal: skip

        int ktmax = ((dq + 15) >> 4) + 1;
        if (ktmax > 4) ktmax = 4;
        int ktfull = (dq - 15) >= 0 ? ((dq - 15) >> 4) + 1 : 0;
        if (ktfull > 4) ktfull = 4;
        const short* Kc = &Ks[cur][0];
        const short* Vc = &Vt[cur][0];

        // ---- S = Q K^T for live tiles
        f32x4 S[4];
#pragma unroll
        for (int kt = 0; kt < 4; ++kt) {
            if (kt >= ktmax) break;
            const bf16x8 bk0 = *(const bf16x8*)&Kc[(kt * 16 + l15) * 64 + ((quad ^ s7) << 3)];
            const bf16x8 bk1 = *(const bf16x8*)&Kc[(kt * 16 + l15) * 64 + (((4 | quad) ^ s7) << 3)];
            f32x4 z = {0.f, 0.f, 0.f, 0.f};
            z = __builtin_amdgcn_mfma_f32_16x16x32_bf16(aq[0], bk0, z, 0, 0, 0);
            S[kt] = __builtin_amdgcn_mfma_f32_16x16x32_bf16(aq[1], bk1, z, 0, 0, 0);
        }
        // ---- scale + mask-bias + (diagonal-only) causal
#pragma unroll
        for (int kt = 0; kt < 4; ++kt) {
            if (kt >= ktmax) break;
            const float bv = bias[kb + kt * 16 + l15];
#pragma unroll
            for (int rg = 0; rg < 4; ++rg) {
                float s = fmaf(S[kt][rg], 0.125f, bv);
                if (kt >= ktfull) {
                    const int key = kb + kt * 16 + l15;
                    const int qrow = q0 + quad * 4 + rg;
                    s = (key <= qrow) ? s : BIGNEG;
                }
                S[kt][rg] = s;
            }
        }
        // ---- online softmax (16-lane row reductions)
        float alpha[4];
#pragma unroll
        for (int rg = 0; rg < 4; ++rg) {
            float v = BIGNEG;
#pragma unroll
            for (int kt = 0; kt < 4; ++kt)
                if (kt < ktmax) v = fmaxf(v, S[kt][rg]);
            v = fmaxf(v, __shfl_xor(v, 1));
            v = fmaxf(v, __shfl_xor(v, 2));
            v = fmaxf(v, __shfl_xor(v, 4));
            v = fmaxf(v, __shfl_xor(v, 8));
            const float mn = fmaxf(m_r[rg], v);
            alpha[rg] = __expf(m_r[rg] - mn);
            m_r[rg] = mn;
            l_r[rg] *= alpha[rg];
        }
#pragma unroll
        for (int kt = 0; kt < 4; ++kt) {
            if (kt >= ktmax) break;
#pragma unroll
            for (int rg = 0; rg < 4; ++rg)
                S[kt][rg] = __expf(S[kt][rg] - m_r[rg]);
        }
#pragma unroll
        for (int rg = 0; rg < 4; ++rg) {
            float v = 0.f;
#pragma unroll
            for (int kt = 0; kt < 4; ++kt)
                if (kt < ktmax) v += S[kt][rg];
            v += __shfl_xor(v, 1);
            v += __shfl_xor(v, 2);
            v += __shfl_xor(v, 4);
            v += __shfl_xor(v, 8);
            l_r[rg] += v;
        }
        // ---- rescale O
#pragma unroll
        for (int nt = 0; nt < 4; ++nt)
#pragma unroll
            for (int rg = 0; rg < 4; ++rg)
                O[nt][rg] *= alpha[rg];

        // ---- P: C-layout regs -> per-wave swizzled LDS (wave-private)
        short* Pw = &Ps[wave][0];
        asm volatile("s_waitcnt lgkmcnt(0)" ::: "memory");  // prev PV reads of Ps done
#pragma unroll
        for (int kt = 0; kt < 4; ++kt) {
            if (kt >= ktmax) break;
#pragma unroll
            for (int rg = 0; rg < 4; ++rg) {
                const int qr = quad * 4 + rg;
                const int ch = (kt * 2) | (l15 >> 3);
                Pw[(qr << 6) + (((ch ^ (qr & 7)) << 3) | s7)] = (short)f2bu(S[kt][rg]);
            }
        }
        const int kkmax = (ktmax + 1) >> 1;
        if (ktmax & 1) {   // zero-fill phantom tile so PV runs in 32-key steps
#pragma unroll
            for (int rg = 0; rg < 4; ++rg) {
                const int qr = quad * 4 + rg;
                const int ch = (ktmax * 2) | (l15 >> 3);
                Pw[(qr << 6) + (((ch ^ (qr & 7)) << 3) | s7)] = 0;
            }
        }
        asm volatile("s_waitcnt lgkmcnt(0)" ::: "memory");  // P visible to own reads
        // ---- O += P V
#pragma unroll
        for (int kk = 0; kk < 2; ++kk) {
            if (kk >= kkmax) break;
            const bf16x8 ap = *(const bf16x8*)&Pw[(l15 << 6) + ((((kk << 2) | quad) ^ s7) << 3)];
#pragma unroll
            for (int nt = 0; nt < 4; ++nt) {
                const bf16x8 bv = *(const bf16x8*)&Vc[(nt * 16 + l15) * 64 +
                                                     ((((kk << 2) | quad) ^ s7) << 3)];
                O[nt] = __builtin_amdgcn_mfma_f32_16x16x32_bf16(ap, bv, O[nt], 0, 0, 0);
            }
        }
    }

    // epilogue: O /= l, write bf16
#pragma unroll
    for (int rg = 0; rg < 4; ++rg) {
        const int q = q0 + quad * 4 + rg;
        const float inv = 1.f / l_r[rg];
        unsigned short* op = (unsigned short*)attnb + (size_t)(b * SS + q) * 1024 + h * 64;
#pragma unroll
        for (int nt = 0; nt < 4; ++nt)
            op[nt * 16 + l15] = f2bu(O[nt][rg] * inv);
    }
}

// ---------------------------------------------------------------------------
// Launch. Workspace plan (60 MB peak), offsets in bytes:
//   [0,6M)   Wqkv_t bf16 [3072][1024]
//   [6,8M)   Wo_t   bf16 [1024][1024]
//   [8,16M)  W1_t   bf16 [4096][1024]
//   [16,20M) W2_t   bf16 [1024][2048]
//   [20,28M) lnb    bf16 (ln1 then ln2)
//   [28,44M) qkb    bf16 [4096][2048] (q|k)  -> dead after flash
//   [44,52M) VT     bf16 [1024][4096] (v^T)  -> dead after flash
//   [52,60M) attnb  bf16                     -> dead after Wo gemm
//   [28,44M) x1     fp32 (reuses qkb)
//   [44,52M) glub   bf16 (reuses VT)
// ---------------------------------------------------------------------------
extern "C" void kernel_launch(void* const* d_in, const int* in_sizes, int n_in,
                              void* d_out, int out_size, void* d_ws, size_t ws_size,
                              hipStream_t stream) {
    const float* x  = (const float*)d_in[0];
    const int* mask = (const int*)d_in[1];
    const float* Wq = (const float*)d_in[2];
    const float* Wk = (const float*)d_in[3];
    const float* Wv = (const float*)d_in[4];
    const float* Wo = (const float*)d_in[5];
    const float* W1 = (const float*)d_in[6];
    const float* W2 = (const float*)d_in[7];
    const float* g1 = (const float*)d_in[8];
    const float* b1 = (const float*)d_in[9];
    const float* g2 = (const float*)d_in[10];
    const float* b2 = (const float*)d_in[11];

    const size_t MB = 1024 * 1024;
    uint8_t* ws = (uint8_t*)d_ws;
    __hip_bfloat16* wqkvt = (__hip_bfloat16*)(ws);
    __hip_bfloat16* wot   = (__hip_bfloat16*)(ws + 6 * MB);
    __hip_bfloat16* w1t   = (__hip_bfloat16*)(ws + 8 * MB);
    __hip_bfloat16* w2t   = (__hip_bfloat16*)(ws + 16 * MB);
    __hip_bfloat16* lnb   = (__hip_bfloat16*)(ws + 20 * MB);
    __hip_bfloat16* qkb   = (__hip_bfloat16*)(ws + 28 * MB);
    float*          x1    = (float*)(ws + 28 * MB);
    __hip_bfloat16* VT    = (__hip_bfloat16*)(ws + 44 * MB);
    __hip_bfloat16* glub  = (__hip_bfloat16*)(ws + 44 * MB);
    __hip_bfloat16* attnb = (__hip_bfloat16*)(ws + 52 * MB);

    // 0. all weight transposes in one launch
    transpose_all<<<10240, 256, 0, stream>>>(Wq, Wk, Wv, Wo, W1, W2, wqkvt, wot, w1t, w2t);

    // 1. ln1 = LN(x) -> lnb
    ln_kernel<<<NTOK, 256, 0, stream>>>(x, g1, b1, lnb);

    // 2. qkv GEMM: q,k -> qkb; v -> VT (transposed)
    mfma_gemm<0, 3><<<dim3(24, 32), 256, 0, stream>>>(lnb, wqkvt, VT, qkb, NTOK, 3072, 1024);

    // 3. MFMA flash attention -> attnb (1024 blocks, XCD-aware, dbuf)
    flash_mfma<<<1024, 256, 0, stream>>>(qkb, VT, mask, attnb);

    // 4. x1 = x + attn @ Wo -> x1 (fp32)
    mfma_gemm<1, 0><<<dim3(8, 32), 256, 0, stream>>>(attnb, wot, x, x1, NTOK, 1024, 1024);

    // 5. ln2 = LN(x1) -> lnb
    ln_kernel<<<NTOK, 256, 0, stream>>>(x1, g2, b2, lnb);

    // 6. glu = (ln2@W1L) * sigmoid(ln2@W1R) -> glub
    mfma_gemm_glu<<<dim3(16, 32), 256, 0, stream>>>(lnb, w1t, glub);

    // 7. out = x1 + glu @ W2 -> d_out (fp32)
    mfma_gemm<1, 0><<<dim3(8, 32), 256, 0, stream>>>(glub, w2t, x1, (float*)d_out,
                                                     NTOK, 1024, 2048);
}

// Round 10
// 351.322 us; speedup vs baseline: 1.5986x; 1.0002x over previous
//
#include <hip/hip_runtime.h>
#include <hip/hip_bf16.h>
#include <math.h>

// Problem constants (B=2, S=2048, D=1024, H=16, DH=64)
#define BB 2
#define SS 2048
#define DD 1024
#define HH 16
#define DH 64
#define NTOK (BB * SS)   // 4096
#define LN_EPS 1e-5f
#define BIGNEG -1e30f

typedef __attribute__((ext_vector_type(8))) short bf16x8;   // 8 bf16 = 4 VGPRs
typedef __attribute__((ext_vector_type(4))) float f32x4;    // MFMA accumulator

static __device__ __forceinline__ unsigned short f2bu(float f) {
    __hip_bfloat16 h = __float2bfloat16(f);
    return *(unsigned short*)&h;
}

// async 16B global -> LDS. LDS dest is wave-uniform base + lane*16 by construction.
static __device__ __forceinline__ void async16(const void* g, void* l) {
    __builtin_amdgcn_global_load_lds((const __attribute__((address_space(1))) void*)g,
                                     (__attribute__((address_space(3))) void*)l, 16, 0, 0);
}

// XOR-swizzle: DMA-staged LDS rows are 128B apart (bank 0 every row).
// Store chunk (row, d) at (row, d ^ (row&7)), read back at d ^ (row&7):
// b128 reads spread over all 8 4-bank groups (2-way, free). r9: conflicts = 0.

// ---------------------------------------------------------------------------
// Merged prep: weight transpose+cast (blocks 0..10239) + LN1 (blocks 10240+).
// ---------------------------------------------------------------------------
__global__ __launch_bounds__(256) void prep_kernel(const float* __restrict__ Wq,
                                                   const float* __restrict__ Wk,
                                                   const float* __restrict__ Wv,
                                                   const float* __restrict__ Wo,
                                                   const float* __restrict__ W1,
                                                   const float* __restrict__ W2,
                                                   __hip_bfloat16* __restrict__ wqkvt,
                                                   __hip_bfloat16* __restrict__ wot,
                                                   __hip_bfloat16* __restrict__ w1t,
                                                   __hip_bfloat16* __restrict__ w2t,
                                                   const float* __restrict__ x,
                                                   const float* __restrict__ gamma,
                                                   const float* __restrict__ beta,
                                                   __hip_bfloat16* __restrict__ lnb) {
    __shared__ float t[32][33];
    __shared__ float red[256];
    const int bid = blockIdx.x;
    const int tid = threadIdx.x;

    if (bid >= 10240) {
        // ---- LayerNorm row
        const int row = bid - 10240;
        const float* xp = x + (size_t)row * DD;
        float vals[4];
        float s = 0.f;
#pragma unroll
        for (int i = 0; i < 4; ++i) {
            float v = xp[tid + i * 256];
            vals[i] = v;
            s += v;
        }
        red[tid] = s;
        __syncthreads();
        for (int st = 128; st > 0; st >>= 1) {
            if (tid < st) red[tid] += red[tid + st];
            __syncthreads();
        }
        const float mu = red[0] * (1.0f / DD);
        __syncthreads();
        float sq = 0.f;
#pragma unroll
        for (int i = 0; i < 4; ++i) {
            float d = vals[i] - mu;
            sq += d * d;
        }
        red[tid] = sq;
        __syncthreads();
        for (int st = 128; st > 0; st >>= 1) {
            if (tid < st) red[tid] += red[tid + st];
            __syncthreads();
        }
        const float rinv = rsqrtf(red[0] * (1.0f / DD) + LN_EPS);
        __hip_bfloat16* op = lnb + (size_t)row * DD;
#pragma unroll
        for (int i = 0; i < 4; ++i) {
            int j = tid + i * 256;
            op[j] = __float2bfloat16(gamma[j] * ((vals[i] - mu) * rinv) + beta[j]);
        }
        return;
    }

    // ---- weight transpose tile
    const float* W;
    __hip_bfloat16* Wt;
    int K, N, tile;
    if (bid < 4096) {
        const int m = bid >> 10;
        tile = bid & 1023;
        W = (m == 0) ? Wq : (m == 1) ? Wk : (m == 2) ? Wv : Wo;
        Wt = (m < 3) ? (wqkvt + (size_t)m * 1024 * 1024) : wot;
        K = 1024; N = 1024;
    } else if (bid < 8192) {
        tile = bid - 4096; W = W1; Wt = w1t; K = 1024; N = 4096;
    } else {
        tile = bid - 8192; W = W2; Wt = w2t; K = 2048; N = 1024;
    }
    const int nt = N >> 5;
    const int n0 = (tile % nt) * 32, k0 = (tile / nt) * 32;
    const int tx = tid & 31, ty = tid >> 5;
#pragma unroll
    for (int i = 0; i < 4; ++i)
        t[ty + 8 * i][tx] = W[(size_t)(k0 + ty + 8 * i) * N + n0 + tx];
    __syncthreads();
#pragma unroll
    for (int i = 0; i < 4; ++i)
        Wt[(size_t)(n0 + ty + 8 * i) * K + k0 + tx] = __float2bfloat16(t[tx][ty + 8 * i]);
}

// ---------------------------------------------------------------------------
// LayerNorm fp32 -> bf16 (standalone, for ln2). One block per row.
// ---------------------------------------------------------------------------
__global__ __launch_bounds__(256) void ln_kernel(const float* __restrict__ x,
                                                 const float* __restrict__ gamma,
                                                 const float* __restrict__ beta,
                                                 __hip_bfloat16* __restrict__ out) {
    const int row = blockIdx.x;
    const int tid = threadIdx.x;
    __shared__ float red[256];

    const float* xp = x + (size_t)row * DD;
    float vals[4];
    float s = 0.f;
#pragma unroll
    for (int i = 0; i < 4; ++i) {
        float v = xp[tid + i * 256];
        vals[i] = v;
        s += v;
    }
    red[tid] = s;
    __syncthreads();
    for (int st = 128; st > 0; st >>= 1) {
        if (tid < st) red[tid] += red[tid + st];
        __syncthreads();
    }
    const float mu = red[0] * (1.0f / DD);
    __syncthreads();
    float sq = 0.f;
#pragma unroll
    for (int i = 0; i < 4; ++i) {
        float d = vals[i] - mu;
        sq += d * d;
    }
    red[tid] = sq;
    __syncthreads();
    for (int st = 128; st > 0; st >>= 1) {
        if (tid < st) red[tid] += red[tid + st];
        __syncthreads();
    }
    const float rinv = rsqrtf(red[0] * (1.0f / DD) + LN_EPS);

    __hip_bfloat16* op = out + (size_t)row * DD;
#pragma unroll
    for (int i = 0; i < 4; ++i) {
        int j = tid + i * 256;
        op[j] = __float2bfloat16(gamma[j] * ((vals[i] - mu) * rinv) + beta[j]);
    }
}

// ---------------------------------------------------------------------------
// V transpose: VT[c][t] = qkvb[t][2048 + c]  (bf16, 64x64 LDS tiles, both
// sides coalesced). c in [0,1024) = h*64+d, t in [0,4096).
// ---------------------------------------------------------------------------
__global__ __launch_bounds__(256) void vtrans(const __hip_bfloat16* __restrict__ qkvb_,
                                              __hip_bfloat16* __restrict__ VT_) {
    const unsigned short* src = (const unsigned short*)qkvb_;
    unsigned short* dst = (unsigned short*)VT_;
    __shared__ unsigned short t[64][65];
    const int c0 = (blockIdx.x & 15) << 6;
    const int t0 = (blockIdx.x >> 4) << 6;
    const int tx = threadIdx.x & 63, ty = threadIdx.x >> 6;
#pragma unroll
    for (int i = 0; i < 16; ++i)
        t[ty + 4 * i][tx] = src[(size_t)(t0 + ty + 4 * i) * 3072 + 2048 + c0 + tx];
    __syncthreads();
#pragma unroll
    for (int i = 0; i < 16; ++i)
        dst[(size_t)(c0 + ty + 4 * i) * 4096 + t0 + tx] = t[tx][ty + 4 * i];
}

// ---------------------------------------------------------------------------
// MFMA bf16 GEMM (m97 structure + XOR-swizzled LDS staging).
// C[M,N] = A[M,K] @ Bt[N,K]^T. 128x128 tile, 4 waves, BK=64.
// RES: 0 none, 1 add fp32 res[oi].  EPI: 0 fp32 out, 1 bf16 out.
// ---------------------------------------------------------------------------
template <int RES, int EPI>
__global__ __launch_bounds__(256) void mfma_gemm(const __hip_bfloat16* __restrict__ A,
                                                 const __hip_bfloat16* __restrict__ Bt,
                                                 const void* __restrict__ res,
                                                 void* __restrict__ out,
                                                 int M, int N, int K) {
    __shared__ short As[128 * 64];
    __shared__ short Bs[128 * 64];
    const int tid = threadIdx.x;
    const int lane = tid & 63;
    const int wave = tid >> 6;
    const int row0 = blockIdx.y * 128;
    const int col0 = blockIdx.x * 128;
    const int wr = (wave >> 1) * 64;
    const int wc = (wave & 1) * 64;
    const int l15 = lane & 15;
    const int quad = lane >> 4;
    const int s7 = l15 & 7;

    f32x4 acc[4][4] = {};

    for (int k0 = 0; k0 < K; k0 += 64) {
#pragma unroll
        for (int r = 0; r < 4; ++r) {
            const int ec = r * 256 + tid;
            const int ar = ec >> 3, d = ec & 7;
            const int ao = (d ^ (ar & 7)) << 3;     // swizzled source dim offset
            async16(&A[(size_t)(row0 + ar) * K + k0 + ao], &As[ec << 3]);
            async16(&Bt[(size_t)(col0 + ar) * K + k0 + ao], &Bs[ec << 3]);
        }
        __syncthreads();
#pragma unroll
        for (int kk = 0; kk < 2; ++kk) {
            const int co = (((kk << 2) | quad) ^ s7) << 3;  // swizzled chunk offset
            bf16x8 af[4], bfr[4];
#pragma unroll
            for (int i = 0; i < 4; ++i)
                af[i] = *(const bf16x8*)&As[(wr + i * 16 + l15) * 64 + co];
#pragma unroll
            for (int j = 0; j < 4; ++j)
                bfr[j] = *(const bf16x8*)&Bs[(wc + j * 16 + l15) * 64 + co];
#pragma unroll
            for (int i = 0; i < 4; ++i)
#pragma unroll
                for (int j = 0; j < 4; ++j)
                    acc[i][j] = __builtin_amdgcn_mfma_f32_16x16x32_bf16(af[i], bfr[j], acc[i][j], 0, 0, 0);
        }
        __syncthreads();
    }

    const int r4 = quad * 4;
#pragma unroll
    for (int i = 0; i < 4; ++i) {
#pragma unroll
        for (int j = 0; j < 4; ++j) {
            const int orow0 = row0 + wr + i * 16 + r4;
            const int ocol = col0 + wc + j * 16 + l15;
#pragma unroll
            for (int rg = 0; rg < 4; ++rg) {
                const size_t oi = (size_t)(orow0 + rg) * N + ocol;
                float v = acc[i][j][rg];
                if constexpr (RES == 1) v += ((const float*)res)[oi];
                if constexpr (EPI == 0) ((float*)out)[oi] = v;
                if constexpr (EPI == 1) ((__hip_bfloat16*)out)[oi] = __float2bfloat16(v);
            }
        }
    }
}

// ---------------------------------------------------------------------------
// Fused FFN-in GEMM+GLU (swizzled staging): glu = (A@W1L^T) * sigmoid(A@W1R^T).
// ---------------------------------------------------------------------------
__global__ __launch_bounds__(256) void mfma_gemm_glu(const __hip_bfloat16* __restrict__ A,
                                                     const __hip_bfloat16* __restrict__ Bt,
                                                     __hip_bfloat16* __restrict__ out) {
    __shared__ short As[128 * 64];
    __shared__ short Bl[128 * 64];
    __shared__ short Br[128 * 64];
    const int tid = threadIdx.x;
    const int lane = tid & 63;
    const int wave = tid >> 6;
    const int row0 = blockIdx.y * 128;
    const int col0 = blockIdx.x * 128;
    const int wr = (wave >> 1) * 64;
    const int wc = (wave & 1) * 64;
    const int l15 = lane & 15;
    const int quad = lane >> 4;
    const int s7 = l15 & 7;

    f32x4 accl[4][4] = {};
    f32x4 accr[4][4] = {};

    for (int k0 = 0; k0 < 1024; k0 += 64) {
#pragma unroll
        for (int r = 0; r < 4; ++r) {
            const int ec = r * 256 + tid;
            const int ar = ec >> 3, d = ec & 7;
            const int ao = (d ^ (ar & 7)) << 3;
            async16(&A[(size_t)(row0 + ar) * 1024 + k0 + ao], &As[ec << 3]);
            async16(&Bt[(size_t)(col0 + ar) * 1024 + k0 + ao], &Bl[ec << 3]);
            async16(&Bt[(size_t)(2048 + col0 + ar) * 1024 + k0 + ao], &Br[ec << 3]);
        }
        __syncthreads();
#pragma unroll
        for (int kk = 0; kk < 2; ++kk) {
            const int co = (((kk << 2) | quad) ^ s7) << 3;
            bf16x8 af[4], bl[4], br[4];
#pragma unroll
            for (int i = 0; i < 4; ++i)
                af[i] = *(const bf16x8*)&As[(wr + i * 16 + l15) * 64 + co];
#pragma unroll
            for (int j = 0; j < 4; ++j) {
                bl[j] = *(const bf16x8*)&Bl[(wc + j * 16 + l15) * 64 + co];
                br[j] = *(const bf16x8*)&Br[(wc + j * 16 + l15) * 64 + co];
            }
#pragma unroll
            for (int i = 0; i < 4; ++i)
#pragma unroll
                for (int j = 0; j < 4; ++j) {
                    accl[i][j] = __builtin_amdgcn_mfma_f32_16x16x32_bf16(af[i], bl[j], accl[i][j], 0, 0, 0);
                    accr[i][j] = __builtin_amdgcn_mfma_f32_16x16x32_bf16(af[i], br[j], accr[i][j], 0, 0, 0);
                }
        }
        __syncthreads();
    }

    const int r4 = quad * 4;
#pragma unroll
    for (int i = 0; i < 4; ++i) {
#pragma unroll
        for (int j = 0; j < 4; ++j) {
#pragma unroll
            for (int rg = 0; rg < 4; ++rg) {
                const int orow = row0 + wr + i * 16 + r4 + rg;
                const int ocol = col0 + wc + j * 16 + l15;
                const float l = accl[i][j][rg];
                const float r = accr[i][j][rg];
                out[(size_t)orow * 2048 + ocol] =
                    __float2bfloat16(l * (1.f / (1.f + __expf(-r))));
            }
        }
    }
}

// ---------------------------------------------------------------------------
// MFMA flash attention v7. Same structure as r9 (Tq=64, Tk=64, dbuf, one
// barrier/chunk, swizzled, XCD-aware) + hoisted staging pointers: per-chunk
// staging is 4 async16 + 4 pointer increments (no per-chunk 64-bit address
// rebuild). K read from qkvb (stride 3072), V from pre-transposed VT.
// ---------------------------------------------------------------------------
#define KADV (64 * 3072)
__global__ __launch_bounds__(256, 3) void flash_mfma(const __hip_bfloat16* __restrict__ qkv_,
                                                     const __hip_bfloat16* __restrict__ VT_,
                                                     const int* __restrict__ mask,
                                                     __hip_bfloat16* __restrict__ attnb) {
    const unsigned short* qkv = (const unsigned short*)qkv_;
    const unsigned short* VT = (const unsigned short*)VT_;
    __shared__ __align__(16) short Ks[2][64 * 64];  // [buf][key][dim], swizzled
    __shared__ __align__(16) short Vt[2][64 * 64];  // [buf][dim][key], swizzled
    __shared__ __align__(16) short Ps[4][16 * 64];  // per-wave P, swizzled
    __shared__ float bias[SS];                      // mask -> additive bias

    const int tid = threadIdx.x;
    const int lane = tid & 63;
    const int wave = tid >> 6;
    const int l15 = lane & 15;
    const int quad = lane >> 4;
    const int s7 = l15 & 7;

    // XCD-aware decode: xcd = bid%8; 4 bh per xcd x 32 qt; qt reversed
    const int xcd = blockIdx.x & 7;
    const int slot = blockIdx.x >> 3;
    const int bh = xcd + ((slot & 3) << 3);
    const int qt = 31 - (slot >> 2);
    const int h = bh & 15;
    const int b = bh >> 4;
    const int q0 = qt * 64 + wave * 16;

    // hoisted per-thread staging pointers (chunk 0) + fixed LDS dests
    const int e0 = tid, e1 = 256 + tid;
    const int r0 = e0 >> 3, d0 = e0 & 7, r1 = e1 >> 3, d1 = e1 & 7;
    const unsigned short* kp0 = qkv + (size_t)(b * SS + r0) * 3072 + 1024 + h * 64 + ((d0 ^ (r0 & 7)) << 3);
    const unsigned short* kp1 = qkv + (size_t)(b * SS + r1) * 3072 + 1024 + h * 64 + ((d1 ^ (r1 & 7)) << 3);
    const unsigned short* vp0 = VT + (size_t)(h * 64 + r0) * 4096 + b * SS + ((d0 ^ (r0 & 7)) << 3);
    const unsigned short* vp1 = VT + (size_t)(h * 64 + r1) * 4096 + b * SS + ((d1 ^ (r1 & 7)) << 3);
    short* const kd0a = &Ks[0][e0 << 3]; short* const kd0b = &Ks[1][e0 << 3];
    short* const kd1a = &Ks[0][e1 << 3]; short* const kd1b = &Ks[1][e1 << 3];
    short* const vd0a = &Vt[0][e0 << 3]; short* const vd0b = &Vt[1][e0 << 3];
    short* const vd1a = &Vt[0][e1 << 3]; short* const vd1b = &Vt[1][e1 << 3];

    // mask -> bias row (once per block)
    for (int i = tid; i < SS; i += 256)
        bias[i] = mask[b * SS + i] ? 0.f : BIGNEG;

    // Q fragments (A-layout)
    bf16x8 aq[2];
#pragma unroll
    for (int ks = 0; ks < 2; ++ks)
        aq[ks] = *(const bf16x8*)(qkv + (size_t)(b * SS + q0 + l15) * 3072 +
                                  h * 64 + ks * 32 + quad * 8);

    f32x4 O[4];
    float m_r[4], l_r[4];
#pragma unroll
    for (int i = 0; i < 4; ++i) {
        O[i] = (f32x4){0.f, 0.f, 0.f, 0.f};
        m_r[i] = BIGNEG;
        l_r[i] = 0.f;
    }

    const int nch = qt + 1;

    // stage chunk 0 into buffer 0; advance pointers to chunk 1
    async16(kp0, kd0a); async16(kp1, kd1a);
    async16(vp0, vd0a); async16(vp1, vd1a);
    kp0 += KADV; kp1 += KADV; vp0 += 64; vp1 += 64;

    for (int c = 0; c < nch; ++c) {
        const int cur = c & 1;
        __syncthreads();   // drains chunk-c DMA + chunk-(c-1) LDS reads

        // prefetch chunk c+1 into the other buffer
        if (c + 1 < nch) {
            async16(kp0, cur ? kd0a : kd0b);
            async16(kp1, cur ? kd1a : kd1b);
            async16(vp0, cur ? vd0a : vd0b);
            async16(vp1, cur ? vd1a : vd1b);
            kp0 += KADV; kp1 += KADV; vp0 += 64; vp1 += 64;
        }

        const int kb = c << 6;
        const int dq = q0 - kb;
        if (dq + 15 < 0) continue;             // wave fully above diagonal

        int ktmax = ((dq + 15) >> 4) + 1;
        if (ktmax > 4) ktmax = 4;
        int ktfull = (dq - 15) >= 0 ? ((dq - 15) >> 4) + 1 : 0;
        if (ktfull > 4) ktfull = 4;
        const short* Kc = &Ks[cur][0];
        const short* Vc = &Vt[cur][0];

        // ---- S = Q K^T for live tiles
        f32x4 S[4];
#pragma unroll
        for (int kt = 0; kt < 4; ++kt) {
            if (kt >= ktmax) break;
            const bf16x8 bk0 = *(const bf16x8*)&Kc[(kt * 16 + l15) * 64 + ((quad ^ s7) << 3)];
            const bf16x8 bk1 = *(const bf16x8*)&Kc[(kt * 16 + l15) * 64 + (((4 | quad) ^ s7) << 3)];
            f32x4 z = {0.f, 0.f, 0.f, 0.f};
            z = __builtin_amdgcn_mfma_f32_16x16x32_bf16(aq[0], bk0, z, 0, 0, 0);
            S[kt] = __builtin_amdgcn_mfma_f32_16x16x32_bf16(aq[1], bk1, z, 0, 0, 0);
        }
        // ---- scale + mask-bias + (diagonal-only) causal
#pragma unroll
        for (int kt = 0; kt < 4; ++kt) {
            if (kt >= ktmax) break;
            const float bv = bias[kb + kt * 16 + l15];
#pragma unroll
            for (int rg = 0; rg < 4; ++rg) {
                float s = fmaf(S[kt][rg], 0.125f, bv);
                if (kt >= ktfull) {
                    const int key = kb + kt * 16 + l15;
                    const int qrow = q0 + quad * 4 + rg;
                    s = (key <= qrow) ? s : BIGNEG;
                }
                S[kt][rg] = s;
            }
        }
        // ---- online softmax (16-lane row reductions)
        float alpha[4];
#pragma unroll
        for (int rg = 0; rg < 4; ++rg) {
            float v = BIGNEG;
#pragma unroll
            for (int kt = 0; kt < 4; ++kt)
                if (kt < ktmax) v = fmaxf(v, S[kt][rg]);
            v = fmaxf(v, __shfl_xor(v, 1));
            v = fmaxf(v, __shfl_xor(v, 2));
            v = fmaxf(v, __shfl_xor(v, 4));
            v = fmaxf(v, __shfl_xor(v, 8));
            const float mn = fmaxf(m_r[rg], v);
            alpha[rg] = __expf(m_r[rg] - mn);
            m_r[rg] = mn;
            l_r[rg] *= alpha[rg];
        }
#pragma unroll
        for (int kt = 0; kt < 4; ++kt) {
            if (kt >= ktmax) break;
#pragma unroll
            for (int rg = 0; rg < 4; ++rg)
                S[kt][rg] = __expf(S[kt][rg] - m_r[rg]);
        }
#pragma unroll
        for (int rg = 0; rg < 4; ++rg) {
            float v = 0.f;
#pragma unroll
            for (int kt = 0; kt < 4; ++kt)
                if (kt < ktmax) v += S[kt][rg];
            v += __shfl_xor(v, 1);
            v += __shfl_xor(v, 2);
            v += __shfl_xor(v, 4);
            v += __shfl_xor(v, 8);
            l_r[rg] += v;
        }
        // ---- rescale O
#pragma unroll
        for (int nt = 0; nt < 4; ++nt)
#pragma unroll
            for (int rg = 0; rg < 4; ++rg)
                O[nt][rg] *= alpha[rg];

        // ---- P: C-layout regs -> per-wave swizzled LDS (wave-private)
        short* Pw = &Ps[wave][0];
        asm volatile("s_waitcnt lgkmcnt(0)" ::: "memory");  // prev PV reads done
#pragma unroll
        for (int kt = 0; kt < 4; ++kt) {
            if (kt >= ktmax) break;
#pragma unroll
            for (int rg = 0; rg < 4; ++rg) {
                const int qr = quad * 4 + rg;
                const int ch = (kt * 2) | (l15 >> 3);
                Pw[(qr << 6) + (((ch ^ (qr & 7)) << 3) | s7)] = (short)f2bu(S[kt][rg]);
            }
        }
        const int kkmax = (ktmax + 1) >> 1;
        if (ktmax & 1) {   // zero-fill phantom tile
#pragma unroll
            for (int rg = 0; rg < 4; ++rg) {
                const int qr = quad * 4 + rg;
                const int ch = (ktmax * 2) | (l15 >> 3);
                Pw[(qr << 6) + (((ch ^ (qr & 7)) << 3) | s7)] = 0;
            }
        }
        asm volatile("s_waitcnt lgkmcnt(0)" ::: "memory");  // P visible
        // ---- O += P V
#pragma unroll
        for (int kk = 0; kk < 2; ++kk) {
            if (kk >= kkmax) break;
            const bf16x8 ap = *(const bf16x8*)&Pw[(l15 << 6) + ((((kk << 2) | quad) ^ s7) << 3)];
#pragma unroll
            for (int nt = 0; nt < 4; ++nt) {
                const bf16x8 bv = *(const bf16x8*)&Vc[(nt * 16 + l15) * 64 +
                                                     ((((kk << 2) | quad) ^ s7) << 3)];
                O[nt] = __builtin_amdgcn_mfma_f32_16x16x32_bf16(ap, bv, O[nt], 0, 0, 0);
            }
        }
    }

    // epilogue: O /= l, write bf16
#pragma unroll
    for (int rg = 0; rg < 4; ++rg) {
        const int q = q0 + quad * 4 + rg;
        const float inv = 1.f / l_r[rg];
        unsigned short* op = (unsigned short*)attnb + (size_t)(b * SS + q) * 1024 + h * 64;
#pragma unroll
        for (int nt = 0; nt < 4; ++nt)
            op[nt * 16 + l15] = f2bu(O[nt][rg] * inv);
    }
}

// ---------------------------------------------------------------------------
// Launch. Workspace plan (84 MB peak; 96 MB proven safe in r2), bytes:
//   [0,6M)   Wqkv_t bf16 [3072][1024]
//   [6,8M)   Wo_t   bf16 [1024][1024]
//   [8,16M)  W1_t   bf16 [4096][1024]
//   [16,20M) W2_t   bf16 [1024][2048]
//   [20,28M) lnb    bf16 (ln1 then ln2)
//   [28,52M) qkvb   bf16 [4096][3072]  -> dead after flash
//   [28,44M) x1     fp32 (reuses qkvb head)
//   [52,60M) attnb  bf16               -> dead after Wo gemm
//   [60,68M) VT     bf16 [1024][4096]  -> dead after flash
//   [68,84M) glub   bf16 [4096][2048]
// ---------------------------------------------------------------------------
extern "C" void kernel_launch(void* const* d_in, const int* in_sizes, int n_in,
                              void* d_out, int out_size, void* d_ws, size_t ws_size,
                              hipStream_t stream) {
    const float* x  = (const float*)d_in[0];
    const int* mask = (const int*)d_in[1];
    const float* Wq = (const float*)d_in[2];
    const float* Wk = (const float*)d_in[3];
    const float* Wv = (const float*)d_in[4];
    const float* Wo = (const float*)d_in[5];
    const float* W1 = (const float*)d_in[6];
    const float* W2 = (const float*)d_in[7];
    const float* g1 = (const float*)d_in[8];
    const float* b1 = (const float*)d_in[9];
    const float* g2 = (const float*)d_in[10];
    const float* b2 = (const float*)d_in[11];

    const size_t MB = 1024 * 1024;
    uint8_t* ws = (uint8_t*)d_ws;
    __hip_bfloat16* wqkvt = (__hip_bfloat16*)(ws);
    __hip_bfloat16* wot   = (__hip_bfloat16*)(ws + 6 * MB);
    __hip_bfloat16* w1t   = (__hip_bfloat16*)(ws + 8 * MB);
    __hip_bfloat16* w2t   = (__hip_bfloat16*)(ws + 16 * MB);
    __hip_bfloat16* lnb   = (__hip_bfloat16*)(ws + 20 * MB);
    __hip_bfloat16* qkvb  = (__hip_bfloat16*)(ws + 28 * MB);
    float*          x1    = (float*)(ws + 28 * MB);
    __hip_bfloat16* attnb = (__hip_bfloat16*)(ws + 52 * MB);
    __hip_bfloat16* VT    = (__hip_bfloat16*)(ws + 60 * MB);
    __hip_bfloat16* glub  = (__hip_bfloat16*)(ws + 68 * MB);

    // 0. weight transposes + ln1 in one launch
    prep_kernel<<<10240 + NTOK, 256, 0, stream>>>(Wq, Wk, Wv, Wo, W1, W2,
                                                  wqkvt, wot, w1t, w2t,
                                                  x, g1, b1, lnb);

    // 1. qkv = ln1 @ [Wq|Wk|Wv] -> qkvb (bf16 rows, N=3072)
    mfma_gemm<0, 1><<<dim3(24, 32), 256, 0, stream>>>(lnb, wqkvt, nullptr, qkvb, NTOK, 3072, 1024);

    // 2. VT = V^T (coalesced LDS transpose)
    vtrans<<<1024, 256, 0, stream>>>(qkvb, VT);

    // 3. MFMA flash attention -> attnb
    flash_mfma<<<1024, 256, 0, stream>>>(qkvb, VT, mask, attnb);

    // 4. x1 = x + attn @ Wo -> x1 (fp32)
    mfma_gemm<1, 0><<<dim3(8, 32), 256, 0, stream>>>(attnb, wot, x, x1, NTOK, 1024, 1024);

    // 5. ln2 = LN(x1) -> lnb
    ln_kernel<<<NTOK, 256, 0, stream>>>(x1, g2, b2, lnb);

    // 6. glu = (ln2@W1L) * sigmoid(ln2@W1R) -> glub
    mfma_gemm_glu<<<dim3(16, 32), 256, 0, stream>>>(lnb, w1t, glub);

    // 7. out = x1 + glu @ W2 -> d_out (fp32)
    mfma_gemm<1, 0><<<dim3(8, 32), 256, 0, stream>>>(glub, w2t, x1, (float*)d_out,
                                                     NTOK, 1024, 2048);
}